// Round 1
// baseline (433.438 us; speedup 1.0000x reference)
//
#include <hip/hip_runtime.h>
#include <math.h>

#define BB 4
#define NN 4096
#define DD 128
#define TILE 64
#define NT (NN / TILE)   // 64 tiles per dim

// ---------------- kernel 1: inverse norms of f_s rows ----------------
__global__ __launch_bounds__(256) void k_norms(const float* __restrict__ fs,
                                               float* __restrict__ inv_norm) {
  int row = blockIdx.x * 4 + (threadIdx.x >> 6);   // flat b*N+n
  int lane = threadIdx.x & 63;
  const float2* p = (const float2*)(fs + (size_t)row * DD);
  float2 v = p[lane];
  float s = v.x * v.x + v.y * v.y;
#pragma unroll
  for (int off = 32; off > 0; off >>= 1) s += __shfl_down(s, off);
  if (lane == 0) inv_norm[row] = 1.0f / sqrtf(s);
}

// ---------------- kernel 2: fused tiled GEMM + exp-rowsum + scaled colmax ---
// block computes a 64x64 tile of dots for batch b; writes
//   psum[b][n][tm]  = sum over this m-tile of exp(dot/10)
//   pmaxv/pmaxi[b][m][tn] = max over this n-tile of dot*inv_norm_s[n], argidx
__global__ __launch_bounds__(256) void k_main(const float* __restrict__ fs,
                                              const float* __restrict__ ft,
                                              const float* __restrict__ inv_norm,
                                              float* __restrict__ psum,
                                              float* __restrict__ pmaxv,
                                              int* __restrict__ pmaxi) {
  __shared__ float sA[TILE][DD + 4];   // +4 floats pad: row stride 528B, 16B aligned
  __shared__ float sB[TILE][DD + 4];
  __shared__ float red1[TILE][16];     // row-sum partials
  __shared__ float red2v[TILE][16];    // col-max partials
  __shared__ int   red2i[TILE][16];

  const int tn = blockIdx.x;   // n-tile
  const int tm = blockIdx.y;   // m-tile
  const int b  = blockIdx.z;
  const int t  = threadIdx.x;

  const float* gA = fs + ((size_t)b * NN + (size_t)tn * TILE) * DD;
  const float* gB = ft + ((size_t)b * NN + (size_t)tm * TILE) * DD;

  // cooperative load: 64x128 floats each, 8 float4 per thread, coalesced
#pragma unroll
  for (int i = 0; i < 8; i++) {
    int off = (i * 256 + t) * 4;     // float index in 64x128 row-major tile
    int r = off >> 7, c = off & 127;
    *(float4*)&sA[r][c] = *(const float4*)&gA[off];
    *(float4*)&sB[r][c] = *(const float4*)&gB[off];
  }

  const int tx = t & 15, ty = t >> 4;   // 16x16 thread grid
  const int r0 = ty * 4;                // rows r0..r0+3
  // cols: tx + 16*j  (interleaved -> 2-way LDS banking, free)

  float invn[4];
#pragma unroll
  for (int i = 0; i < 4; i++)
    invn[i] = inv_norm[(size_t)b * NN + (size_t)tn * TILE + r0 + i];

  __syncthreads();

  float acc[4][4] = {};
#pragma unroll 4
  for (int k = 0; k < DD; k += 4) {
    float4 av[4], bv[4];
#pragma unroll
    for (int i = 0; i < 4; i++) av[i] = *(const float4*)&sA[r0 + i][k];
#pragma unroll
    for (int j = 0; j < 4; j++) bv[j] = *(const float4*)&sB[tx + 16 * j][k];
#pragma unroll
    for (int i = 0; i < 4; i++)
#pragma unroll
      for (int j = 0; j < 4; j++)
        acc[i][j] += av[i].x * bv[j].x + av[i].y * bv[j].y +
                     av[i].z * bv[j].z + av[i].w * bv[j].w;
  }

  // per-thread partials into LDS scratch (disjoint from sA/sB; no sync needed yet)
#pragma unroll
  for (int i = 0; i < 4; i++) {
    float s = 0.0f;
#pragma unroll
    for (int j = 0; j < 4; j++) s += __expf(acc[i][j] * 0.1f);
    red1[r0 + i][tx] = s;
  }
#pragma unroll
  for (int j = 0; j < 4; j++) {
    float bvv = -INFINITY; int bi = 0;
#pragma unroll
    for (int i = 0; i < 4; i++) {
      float v = acc[i][j] * invn[i];
      int gi = tn * TILE + r0 + i;
      if (v > bvv) { bvv = v; bi = gi; }   // i ascending -> ties keep smaller n
    }
    red2v[tx + 16 * j][ty] = bvv;
    red2i[tx + 16 * j][ty] = bi;
  }
  __syncthreads();

  if (t < TILE) {                 // reduce one row's exp-sum
    float s = 0.0f;
#pragma unroll
    for (int u = 0; u < 16; u++) s += red1[t][u];
    int n = tn * TILE + t;
    psum[((size_t)b * NN + n) * NT + tm] = s;
  } else if (t < 2 * TILE) {      // reduce one col's max
    int c = t - TILE;
    float bvv = -INFINITY; int bi = 0;
#pragma unroll
    for (int u = 0; u < 16; u++) {   // u ascending == n ascending
      float v = red2v[c][u]; int i2 = red2i[c][u];
      if (v > bvv || (v == bvv && i2 < bi)) { bvv = v; bi = i2; }
    }
    int m = tm * TILE + c;
    pmaxv[((size_t)b * NN + m) * NT + tn] = bvv;
    pmaxi[((size_t)b * NN + m) * NT + tn] = bi;
  }
}

// ---------------- kernel 3: reduce row partial sums -> log(all_exp) --------
__global__ __launch_bounds__(256) void k_rowsum(const float* __restrict__ psum,
                                                float* __restrict__ logall) {
  int row = blockIdx.x * 4 + (threadIdx.x >> 6);
  int lane = threadIdx.x & 63;
  float s = psum[(size_t)row * NT + lane];
#pragma unroll
  for (int off = 32; off > 0; off >>= 1) s += __shfl_down(s, off);
  if (lane == 0) logall[row] = logf(s);
}

// ---------------- kernel 4: reduce col partial maxes -> idx ----------------
__global__ __launch_bounds__(256) void k_argmax(const float* __restrict__ pmaxv,
                                                const int* __restrict__ pmaxi,
                                                int* __restrict__ idx) {
  int row = blockIdx.x * 4 + (threadIdx.x >> 6);   // flat b*N+m
  int lane = threadIdx.x & 63;
  float v = pmaxv[(size_t)row * NT + lane];
  int   i = pmaxi[(size_t)row * NT + lane];
#pragma unroll
  for (int off = 32; off > 0; off >>= 1) {
    float ov = __shfl_down(v, off);
    int   oi = __shfl_down(i, off);
    if (ov > v || (ov == v && oi < i)) { v = ov; i = oi; }
  }
  if (lane == 0) idx[row] = i;
}

// ---------------- kernel 5: per-row loss term, per-block partial sum -------
__global__ __launch_bounds__(256) void k_loss(const float* __restrict__ fs,
                                              const float* __restrict__ ft,
                                              const float* __restrict__ logall,
                                              const int* __restrict__ idx,
                                              float* __restrict__ blockpart) {
  __shared__ float part[4];
  int w = threadIdx.x >> 6;
  int row = blockIdx.x * 4 + w;     // flat b*N+n
  int b = row >> 12;                // N == 4096
  int lane = threadIdx.x & 63;
  int j = idx[row];
  const float2* pa = (const float2*)(fs + (size_t)row * DD);
  const float2* pb = (const float2*)(ft + ((size_t)b * NN + j) * DD);
  float2 a = pa[lane], c = pb[lane];
  float s = a.x * c.x + a.y * c.y;
#pragma unroll
  for (int off = 32; off > 0; off >>= 1) s += __shfl_down(s, off);
  if (lane == 0) {
    float term = logall[row] - s * 0.1f;
    term = fminf(term, 92.103403719761827f);   // ratio clip at 1e-40
    part[w] = term;
  }
  __syncthreads();
  if (threadIdx.x == 0)
    blockpart[blockIdx.x] = part[0] + part[1] + part[2] + part[3];
}

// ---------------- kernel 6: final deterministic reduction ------------------
__global__ __launch_bounds__(256) void k_final(const float* __restrict__ blockpart,
                                               float* __restrict__ out) {
  __shared__ float red[256];
  float s = 0.0f;
  for (int i = threadIdx.x; i < (BB * NN) / 4; i += 256) s += blockpart[i];
  red[threadIdx.x] = s;
  __syncthreads();
  for (int st = 128; st > 0; st >>= 1) {
    if (threadIdx.x < st) red[threadIdx.x] += red[threadIdx.x + st];
    __syncthreads();
  }
  if (threadIdx.x == 0) out[0] = red[0] * (1.0f / (BB * NN));
}

extern "C" void kernel_launch(void* const* d_in, const int* in_sizes, int n_in,
                              void* d_out, int out_size, void* d_ws, size_t ws_size,
                              hipStream_t stream) {
  const float* fs = (const float*)d_in[0];
  const float* ft = (const float*)d_in[1];
  float* out = (float*)d_out;

  // workspace layout (floats/ints)
  float* inv_norm = (float*)d_ws;                            // B*N
  float* logall   = inv_norm + (size_t)BB * NN;              // B*N
  float* psum     = logall + (size_t)BB * NN;                // B*N*NT
  float* pmaxv    = psum + (size_t)BB * NN * NT;             // B*N*NT
  int*   pmaxi    = (int*)(pmaxv + (size_t)BB * NN * NT);    // B*N*NT
  int*   idx      = pmaxi + (size_t)BB * NN * NT;            // B*N
  float* blockpart = (float*)(idx + (size_t)BB * NN);        // B*N/4

  k_norms<<<(BB * NN) / 4, 256, 0, stream>>>(fs, inv_norm);
  dim3 g2(NT, NT, BB);
  k_main<<<g2, 256, 0, stream>>>(fs, ft, inv_norm, psum, pmaxv, pmaxi);
  k_rowsum<<<(BB * NN) / 4, 256, 0, stream>>>(psum, logall);
  k_argmax<<<(BB * NN) / 4, 256, 0, stream>>>(pmaxv, pmaxi, idx);
  k_loss<<<(BB * NN) / 4, 256, 0, stream>>>(fs, ft, logall, idx, blockpart);
  k_final<<<1, 256, 0, stream>>>(blockpart, out);
}

// Round 2
// 90.279 us; speedup vs baseline: 4.8011x; 4.8011x over previous
//
#include <hip/hip_runtime.h>
#include <math.h>

#define BB 4
#define NN 4096
#define DD 128
#define BM 128           // tile edge
#define NTILES (NN / BM) // 32

typedef __attribute__((ext_vector_type(8))) short bf16x8;
typedef __attribute__((ext_vector_type(4))) float f32x4;
typedef __attribute__((ext_vector_type(8))) unsigned short u16x8;

__device__ __forceinline__ void mfma_16x16x32_bf16(f32x4& d, bf16x8 a, bf16x8 b) {
  asm volatile("v_mfma_f32_16x16x32_bf16 %0, %1, %2, %0" : "+v"(d) : "v"(a), "v"(b));
}

__device__ __forceinline__ void gload16(const void* g, void* lds) {
  __builtin_amdgcn_global_load_lds(
      (const __attribute__((address_space(1))) void*)g,
      (__attribute__((address_space(3))) void*)lds, 16, 0, 0);
}

__device__ __forceinline__ unsigned short f2b(float x) {  // RNE f32->bf16
  union { float f; unsigned u; } v; v.f = x;
  unsigned r = v.u + 0x7fffu + ((v.u >> 16) & 1u);
  return (unsigned short)(r >> 16);
}

// ---------------- kernel 0: fp32 -> bf16 cast (vectorized) ----------------
__global__ __launch_bounds__(256) void k_cast(const float* __restrict__ in,
                                              unsigned short* __restrict__ outp,
                                              int n8) {
  int i = blockIdx.x * 256 + threadIdx.x;
  if (i >= n8) return;
  float4 a = *(const float4*)(in + (size_t)i * 8);
  float4 c = *(const float4*)(in + (size_t)i * 8 + 4);
  u16x8 o;
  o[0] = f2b(a.x); o[1] = f2b(a.y); o[2] = f2b(a.z); o[3] = f2b(a.w);
  o[4] = f2b(c.x); o[5] = f2b(c.y); o[6] = f2b(c.z); o[7] = f2b(c.w);
  *(u16x8*)(outp + (size_t)i * 8) = o;
}

// ---------------- kernel 1: inverse norms of f_s rows (fp32) ----------------
__global__ __launch_bounds__(256) void k_norms(const float* __restrict__ fs,
                                               float* __restrict__ inv_norm) {
  int row = blockIdx.x * 4 + (threadIdx.x >> 6);
  int lane = threadIdx.x & 63;
  const float2* p = (const float2*)(fs + (size_t)row * DD);
  float2 v = p[lane];
  float s = v.x * v.x + v.y * v.y;
#pragma unroll
  for (int off = 32; off > 0; off >>= 1) s += __shfl_down(s, off);
  if (lane == 0) inv_norm[row] = 1.0f / sqrtf(s);
}

// ---------------- kernel 2: MFMA GEMM + fused exp-rowsum + scaled colmax ----
// 128x128 dots tile per block. 4 waves in 2x2 (wr,wc), each wave 64x64 via
// 4x4 fragments of v_mfma_f32_16x16x32_bf16 (K = 128 = 4 steps of 32).
__global__ __launch_bounds__(256) void k_main(const unsigned short* __restrict__ fsb,
                                              const unsigned short* __restrict__ ftb,
                                              const float* __restrict__ inv_norm,
                                              float* __restrict__ psum,
                                              float* __restrict__ pmaxv,
                                              int* __restrict__ pmaxi) {
  // LDS: [0,32K) A-tile, [32K,64K) B-tile (both bf16 [128][128], XOR-swizzled),
  // [64K,64K+512) sInv. After the MFMA barrier the A region is reused for
  // reduction scratch: redS f32[128][33] @0, redMv f32[128][9] @16896,
  // redMi i32[128][9] @21504.
  __shared__ __align__(16) char smem[66048];
  char* sA = smem;
  char* sB = smem + 32768;
  float* sInv = (float*)(smem + 65536);

  const int t = threadIdx.x;
  const int tn = blockIdx.x, tm = blockIdx.y, b = blockIdx.z;
  const int w = t >> 6, lane = t & 63;
  const int l15 = lane & 15, g = lane >> 4;
  const int wr = w >> 1, wc = w & 1;

  const char* gA = (const char*)(fsb + ((size_t)b * NN + (size_t)tn * BM) * DD);
  const char* gB = (const char*)(ftb + ((size_t)b * NN + (size_t)tm * BM) * DD);

  // stage 32KB each, contiguous source, involution swizzle on 16B-block col:
  // LDS block (r, c') <- global block (r, c' ^ (r&15))
#pragma unroll
  for (int p = 0; p < 8; p++) {
    int s = p * 256 + t;               // 16B-block index 0..2047
    int r = s >> 4, cp = s & 15;
    int gsoff = r * 256 + (((cp ^ (r & 15))) << 4);
    int loff = p * 4096 + w * 1024;    // wave-uniform LDS base (+lane*16 by HW)
    gload16(gA + gsoff, sA + loff);
    gload16(gB + gsoff, sB + loff);
  }
  if (t < BM) sInv[t] = inv_norm[(size_t)b * NN + (size_t)tn * BM + t];
  __syncthreads();

  f32x4 acc[4][4] = {};
#pragma unroll
  for (int kk = 0; kk < 4; kk++) {
    bf16x8 af[4], bfr[4];
#pragma unroll
    for (int fi = 0; fi < 4; fi++) {
      int Ra = wr * 64 + fi * 16 + l15;
      int Rb = wc * 64 + fi * 16 + l15;
      int ca = (kk * 4 + g) ^ l15;     // swizzled 16B col (R&15 == l15)
      af[fi]  = *(const bf16x8*)(sA + Ra * 256 + ca * 16);
      bfr[fi] = *(const bf16x8*)(sB + Rb * 256 + ca * 16);
    }
#pragma unroll
    for (int fi = 0; fi < 4; fi++)
#pragma unroll
      for (int fj = 0; fj < 4; fj++)
        mfma_16x16x32_bf16(acc[fi][fj], af[fi], bfr[fj]);
  }
  __syncthreads();   // all waves done with sA/sB -> safe to reuse as scratch

  float* redS  = (float*)smem;            // [128][33]
  float* redMv = (float*)(smem + 16896);  // [128][9]
  int*   redMi = (int*)(smem + 21504);    // [128][9]

  // acc[fi][fj][j]: local row rn = wr*64+fi*16+g*4+j, local col cm = wc*64+fj*16+l15
  // row exp-sums (over this wave's 64 cols)
#pragma unroll
  for (int fi = 0; fi < 4; fi++) {
#pragma unroll
    for (int j = 0; j < 4; j++) {
      float s = 0.0f;
#pragma unroll
      for (int fj = 0; fj < 4; fj++) s += __expf(acc[fi][fj][j] * 0.1f);
      int rn = wr * 64 + fi * 16 + g * 4 + j;
      redS[rn * 33 + wc * 16 + l15] = s;
    }
  }
  // col maxes of dot * inv_norm_s[row] (over this wave's 64 rows)
#pragma unroll
  for (int fj = 0; fj < 4; fj++) {
    float bv = -INFINITY; int bi = 0x7fffffff;
#pragma unroll
    for (int fi = 0; fi < 4; fi++) {
#pragma unroll
      for (int j = 0; j < 4; j++) {
        int rn = wr * 64 + fi * 16 + g * 4 + j;
        float v = acc[fi][fj][j] * sInv[rn];
        int gi = tn * BM + rn;
        if (v > bv || (v == bv && gi < bi)) { bv = v; bi = gi; }
      }
    }
    int cm = wc * 64 + fj * 16 + l15;
    redMv[cm * 9 + wr * 4 + g] = bv;
    redMi[cm * 9 + wr * 4 + g] = bi;
  }
  __syncthreads();

  if (t < BM) {                       // finish one row's exp-sum partial
    float s = 0.0f;
#pragma unroll
    for (int u = 0; u < 32; u++) s += redS[t * 33 + u];
    int n = tn * BM + t;
    psum[((size_t)b * NN + n) * NTILES + tm] = s;
  } else {                            // finish one col's max partial
    int c = t - BM;
    float bv = -INFINITY; int bi = 0x7fffffff;
#pragma unroll
    for (int u = 0; u < 8; u++) {
      float v = redMv[c * 9 + u]; int i2 = redMi[c * 9 + u];
      if (v > bv || (v == bv && i2 < bi)) { bv = v; bi = i2; }
    }
    int m = tm * BM + c;
    pmaxv[((size_t)b * NN + m) * NTILES + tn] = bv;
    pmaxi[((size_t)b * NN + m) * NTILES + tn] = bi;
  }
}

// ---------------- kernel 3: reduce 32 row partials -> log(all_exp) ---------
__global__ __launch_bounds__(256) void k_rowsum(const float* __restrict__ psum,
                                                float* __restrict__ logall) {
  int row = blockIdx.x * 8 + (threadIdx.x >> 5);
  int l = threadIdx.x & 31;
  float s = psum[(size_t)row * NTILES + l];
#pragma unroll
  for (int off = 16; off > 0; off >>= 1) s += __shfl_down(s, off);
  if (l == 0) logall[row] = logf(s);
}

// ---------------- kernel 4: reduce 32 col partials -> idx ------------------
__global__ __launch_bounds__(256) void k_argmax(const float* __restrict__ pmaxv,
                                                const int* __restrict__ pmaxi,
                                                int* __restrict__ idx) {
  int row = blockIdx.x * 8 + (threadIdx.x >> 5);
  int l = threadIdx.x & 31;
  float v = pmaxv[(size_t)row * NTILES + l];
  int   i = pmaxi[(size_t)row * NTILES + l];
#pragma unroll
  for (int off = 16; off > 0; off >>= 1) {
    float ov = __shfl_down(v, off);
    int   oi = __shfl_down(i, off);
    if (ov > v || (ov == v && oi < i)) { v = ov; i = oi; }
  }
  if (l == 0) idx[row] = i;
}

// ---------------- kernel 5: per-row loss term (fp32 dot), block partials ---
__global__ __launch_bounds__(256) void k_loss(const float* __restrict__ fs,
                                              const float* __restrict__ ft,
                                              const float* __restrict__ logall,
                                              const int* __restrict__ idx,
                                              float* __restrict__ blockpart) {
  __shared__ float part[4];
  int w = threadIdx.x >> 6;
  int row = blockIdx.x * 4 + w;     // flat b*N+n
  int b = row >> 12;                // N == 4096
  int lane = threadIdx.x & 63;
  int j = idx[row];
  const float2* pa = (const float2*)(fs + (size_t)row * DD);
  const float2* pb = (const float2*)(ft + ((size_t)b * NN + j) * DD);
  float2 a = pa[lane], c = pb[lane];
  float s = a.x * c.x + a.y * c.y;
#pragma unroll
  for (int off = 32; off > 0; off >>= 1) s += __shfl_down(s, off);
  if (lane == 0) {
    float term = logall[row] - s * 0.1f;
    term = fminf(term, 92.103403719761827f);   // ratio clip at 1e-40
    part[w] = term;
  }
  __syncthreads();
  if (threadIdx.x == 0)
    blockpart[blockIdx.x] = part[0] + part[1] + part[2] + part[3];
}

// ---------------- kernel 6: final deterministic reduction ------------------
__global__ __launch_bounds__(256) void k_final(const float* __restrict__ blockpart,
                                               float* __restrict__ out) {
  __shared__ float red[256];
  float s = 0.0f;
  for (int i = threadIdx.x; i < (BB * NN) / 4; i += 256) s += blockpart[i];
  red[threadIdx.x] = s;
  __syncthreads();
  for (int st = 128; st > 0; st >>= 1) {
    if (threadIdx.x < st) red[threadIdx.x] += red[threadIdx.x + st];
    __syncthreads();
  }
  if (threadIdx.x == 0) out[0] = red[0] * (1.0f / (BB * NN));
}

extern "C" void kernel_launch(void* const* d_in, const int* in_sizes, int n_in,
                              void* d_out, int out_size, void* d_ws, size_t ws_size,
                              hipStream_t stream) {
  const float* fs = (const float*)d_in[0];
  const float* ft = (const float*)d_in[1];
  float* out = (float*)d_out;

  const size_t NE = (size_t)BB * NN * DD;   // 2,097,152 elements per input
  // workspace layout
  unsigned short* fsb = (unsigned short*)d_ws;                  // 4MB
  unsigned short* ftb = fsb + NE;                               // 4MB
  float* inv_norm = (float*)(ftb + NE);                         // 64KB
  float* logall   = inv_norm + (size_t)BB * NN;                 // 64KB
  float* psum     = logall + (size_t)BB * NN;                   // 2MB
  float* pmaxv    = psum + (size_t)BB * NN * NTILES;            // 2MB
  int*   pmaxi    = (int*)(pmaxv + (size_t)BB * NN * NTILES);   // 2MB
  int*   idx      = pmaxi + (size_t)BB * NN * NTILES;           // 64KB
  float* blockpart = (float*)(idx + (size_t)BB * NN);           // 16KB

  int n8 = (int)(NE / 8);
  k_cast<<<(n8 + 255) / 256, 256, 0, stream>>>(fs, fsb, n8);
  k_cast<<<(n8 + 255) / 256, 256, 0, stream>>>(ft, ftb, n8);
  k_norms<<<(BB * NN) / 4, 256, 0, stream>>>(fs, inv_norm);
  dim3 g2(NTILES, NTILES, BB);
  k_main<<<g2, 256, 0, stream>>>(fsb, ftb, inv_norm, psum, pmaxv, pmaxi);
  k_rowsum<<<(BB * NN) / 8, 256, 0, stream>>>(psum, logall);
  k_argmax<<<(BB * NN) / 8, 256, 0, stream>>>(pmaxv, pmaxi, idx);
  k_loss<<<(BB * NN) / 4, 256, 0, stream>>>(fs, ft, logall, idx, blockpart);
  k_final<<<1, 256, 0, stream>>>(blockpart, out);
}

// Round 3
// 60.355 us; speedup vs baseline: 7.1814x; 1.4958x over previous
//
#include <hip/hip_runtime.h>
#include <math.h>

#define BB 4
#define NN 4096
#define DD 128
#define BM 128            // tile edge (rows n per block, cols m per iteration)
#define MSPLIT 4          // m-space split across blocks
#define NIT 8             // B-tiles per block
#define NTT 32            // total m tiles (= n tiles) = MSPLIT*NIT

typedef __attribute__((ext_vector_type(8))) short bf16x8;
typedef __attribute__((ext_vector_type(4))) float f32x4;

__device__ __forceinline__ void mfma_16x16x32_bf16(f32x4& d, bf16x8 a, bf16x8 b) {
  asm volatile("v_mfma_f32_16x16x32_bf16 %0, %1, %2, %0" : "+v"(d) : "v"(a), "v"(b));
}

__device__ __forceinline__ void gload16(const void* g, void* lds) {
  __builtin_amdgcn_global_load_lds(
      (const __attribute__((address_space(1))) void*)g,
      (__attribute__((address_space(3))) void*)lds, 16, 0, 0);
}

__device__ __forceinline__ unsigned short f2b(float x) {  // RNE f32->bf16
  union { float f; unsigned u; } v; v.f = x;
  unsigned r = v.u + 0x7fffu + ((v.u >> 16) & 1u);
  return (unsigned short)(r >> 16);
}

// ---- kernel 1: cast both inputs to bf16 (ft pre-scaled by 0.1) + fs norms --
// one wave per 128-elem row; rows [0,16384) = fs, [16384,32768) = ft.
__global__ __launch_bounds__(256) void k_prep(const float* __restrict__ fs,
                                              const float* __restrict__ ft,
                                              unsigned* __restrict__ outb,
                                              float* __restrict__ inv_norm) {
  int w = threadIdx.x >> 6, lane = threadIdx.x & 63;
  int row = blockIdx.x * 4 + w;
  bool is_s = row < BB * NN;
  const float* src = is_s ? fs + (size_t)row * DD
                          : ft + ((size_t)row - BB * NN) * DD;
  float2 v = ((const float2*)src)[lane];
  float cx = is_s ? v.x : v.x * 0.1f;
  float cy = is_s ? v.y : v.y * 0.1f;
  outb[(size_t)row * 64 + lane] = ((unsigned)f2b(cy) << 16) | f2b(cx);
  if (is_s) {
    float s = v.x * v.x + v.y * v.y;
#pragma unroll
    for (int off = 32; off > 0; off >>= 1) s += __shfl_xor(s, off);
    if (lane == 0) inv_norm[row] = 1.0f / sqrtf(s);
  }
}

// ---- kernel 2: persistent-A MFMA GEMM + fused exp-rowsum + scaled colmax ---
// block = (tn, h, b): A tile (128 n-rows) in registers, loops 8 m-tiles with
// double-buffered global_load_lds prefetch. ft was pre-scaled by 0.1 so
// acc == dots/temp directly; argmax of acc*inv_norm == argmax of sim.
__global__ __launch_bounds__(256, 2) void k_main(const unsigned short* __restrict__ fsb,
                                                 const unsigned short* __restrict__ ftb,
                                                 const float* __restrict__ inv_norm,
                                                 float* __restrict__ psum,
                                                 float* __restrict__ pmaxv,
                                                 int* __restrict__ pmaxi) {
  __shared__ __align__(16) char smem[69120];
  char* buf0 = smem;
  char* buf1 = smem + 32768;
  float* colV = (float*)(smem + 65536);   // [128][2]
  int*   colI = (int*)(smem + 66560);     // [128][2]
  float* rowS = (float*)(smem + 67584);   // [128][2]
  float* sInv = (float*)(smem + 68608);   // [128]

  const int t = threadIdx.x;
  const int tn = blockIdx.x, h = blockIdx.y, b = blockIdx.z;
  const int w = t >> 6, lane = t & 63;
  const int l15 = lane & 15, g = lane >> 4;
  const int wr = w >> 1, wc = w & 1;
  const int rnb = wr * 64 + g * 4;        // row base for this thread's acc rows

  const char* gA = (const char*)(fsb + ((size_t)b * NN + (size_t)tn * BM) * DD);
  const char* gBbase = (const char*)(ftb + ((size_t)b * NN + (size_t)h * NIT * BM) * DD);

  // stage A -> buf1 and B tile 0 -> buf0 (involution swizzle on 16B-block col)
#pragma unroll
  for (int p = 0; p < 8; p++) {
    int s = p * 256 + t;
    int r = s >> 4, cp = s & 15;
    int gsoff = r * 256 + ((cp ^ (r & 15)) << 4);
    int loff = p * 4096 + w * 1024;       // wave-uniform base (+lane*16 by HW)
    gload16(gA + gsoff, buf1 + loff);
    gload16(gBbase + gsoff, buf0 + loff);
  }
  if (t < BM) sInv[t] = inv_norm[(size_t)b * NN + (size_t)tn * BM + t];
  __syncthreads();

  // A fragments + per-row scales into registers
  bf16x8 af[4][4];
#pragma unroll
  for (int kk = 0; kk < 4; kk++)
#pragma unroll
    for (int fi = 0; fi < 4; fi++) {
      int Ra = wr * 64 + fi * 16 + l15;
      int ca = (kk * 4 + g) ^ l15;
      af[kk][fi] = *(const bf16x8*)(buf1 + Ra * 256 + ca * 16);
    }
  float sv[4][4];
#pragma unroll
  for (int fi = 0; fi < 4; fi++)
#pragma unroll
    for (int j = 0; j < 4; j++) sv[fi][j] = sInv[rnb + fi * 16 + j];
  __syncthreads();   // af reads done -> buf1 free for prefetch

  float rowacc[4][4] = {};
  char* cb = buf0;   // compute buffer
  char* nb = buf1;   // prefetch buffer

  for (int it = 0; it < NIT; ++it) {
    // 1. prefetch next B tile
    if (it + 1 < NIT) {
      const char* gBn = gBbase + (size_t)(it + 1) * (BM * DD * 2);
#pragma unroll
      for (int p = 0; p < 8; p++) {
        int s = p * 256 + t;
        int r = s >> 4, cp = s & 15;
        int gsoff = r * 256 + ((cp ^ (r & 15)) << 4);
        int loff = p * 4096 + w * 1024;
        gload16(gBn + gsoff, nb + loff);
      }
    }
    // 2. MFMA on current tile
    f32x4 acc[4][4] = {};
#pragma unroll
    for (int kk = 0; kk < 4; kk++) {
      bf16x8 bfr[4];
#pragma unroll
      for (int fj = 0; fj < 4; fj++) {
        int Rb = wc * 64 + fj * 16 + l15;
        int ca = (kk * 4 + g) ^ l15;
        bfr[fj] = *(const bf16x8*)(cb + Rb * 256 + ca * 16);
      }
#pragma unroll
      for (int fi = 0; fi < 4; fi++)
#pragma unroll
        for (int fj = 0; fj < 4; fj++)
          mfma_16x16x32_bf16(acc[fi][fj], af[kk][fi], bfr[fj]);
    }
    // 3a. exp row-sums accumulate in registers (acc already = dots/temp)
#pragma unroll
    for (int fi = 0; fi < 4; fi++)
#pragma unroll
      for (int j = 0; j < 4; j++) {
        float s = 0.0f;
#pragma unroll
        for (int fj = 0; fj < 4; fj++) s += __expf(acc[fi][fj][j]);
        rowacc[fi][j] += s;
      }
    // 3b. column argmax of acc * inv_norm_row (strict > + ascending = first max)
#pragma unroll
    for (int fj = 0; fj < 4; fj++) {
      float bv = -INFINITY; int bo = 0;
#pragma unroll
      for (int fi = 0; fi < 4; fi++)
#pragma unroll
        for (int j = 0; j < 4; j++) {
          float vv = acc[fi][fj][j] * sv[fi][j];
          if (vv > bv) { bv = vv; bo = fi * 16 + j; }
        }
      int bi = rnb + bo;   // local row 0..127
      // reduce across g lanes (rows interleaved by 4)
#pragma unroll
      for (int off = 16; off <= 32; off <<= 1) {
        float ov = __shfl_xor(bv, off);
        int   oi = __shfl_xor(bi, off);
        if (ov > bv || (ov == bv && oi < bi)) { bv = ov; bi = oi; }
      }
      if (g == 0) {
        int cm = wc * 64 + fj * 16 + l15;
        colV[cm * 2 + wr] = bv;
        colI[cm * 2 + wr] = bi;
      }
    }
    __syncthreads();   // scratch ready; prefetch (vmcnt) drained; cb reads done
    // 4. finalize this tile's column partials
    if (t < BM) {
      float v0 = colV[t * 2], v1 = colV[t * 2 + 1];
      int   i0 = colI[t * 2], i1 = colI[t * 2 + 1];
      bool tk = v1 > v0;             // tie -> wr0 (smaller rows)
      float bv = tk ? v1 : v0;
      int   bi = tk ? i1 : i0;
      int m = (h * NIT + it) * BM + t;
      pmaxv[((size_t)b * NN + m) * NTT + tn] = bv;
      pmaxi[((size_t)b * NN + m) * NTT + tn] = tn * BM + bi;
    }
    __syncthreads();   // scratch reusable; buffer swap safe
    char* tmp = cb; cb = nb; nb = tmp;
  }

  // final row-sum partials: reduce over the 16 column-lanes, combine wc pair
#pragma unroll
  for (int fi = 0; fi < 4; fi++)
#pragma unroll
    for (int j = 0; j < 4; j++) {
      float s = rowacc[fi][j];
#pragma unroll
      for (int off = 1; off <= 8; off <<= 1) s += __shfl_xor(s, off);
      if (l15 == 0) rowS[(rnb + fi * 16 + j) * 2 + wc] = s;
    }
  __syncthreads();
  if (t < BM)
    psum[((size_t)b * NN + tn * BM + t) * MSPLIT + h] = rowS[t * 2] + rowS[t * 2 + 1];
}

// ---- kernel 3: per-row finish: argmax over tn partials, log-sum, pos dot ---
__global__ __launch_bounds__(256) void k_post(const float* __restrict__ fs,
                                              const float* __restrict__ ft,
                                              const float* __restrict__ psum,
                                              const float* __restrict__ pmaxv,
                                              const int* __restrict__ pmaxi,
                                              float* __restrict__ blockpart) {
  __shared__ float part[4];
  int w = threadIdx.x >> 6, lane = threadIdx.x & 63;
  int row = blockIdx.x * 4 + w;          // flat b*N + m
  int b = row >> 12;
  float v = -INFINITY; int i = 0x7fffffff;
  if (lane < NTT) {
    v = pmaxv[(size_t)row * NTT + lane];
    i = pmaxi[(size_t)row * NTT + lane];
  }
#pragma unroll
  for (int off = 16; off > 0; off >>= 1) {
    float ov = __shfl_xor(v, off);
    int   oi = __shfl_xor(i, off);
    if (ov > v || (ov == v && oi < i)) { v = ov; i = oi; }
  }
  int j = __shfl(i, 0);
  // fp32 dot of fs[row] with ft[b, j]
  float2 a = ((const float2*)(fs + (size_t)row * DD))[lane];
  float2 c = ((const float2*)(ft + ((size_t)b * NN + j) * DD))[lane];
  float s = a.x * c.x + a.y * c.y;
#pragma unroll
  for (int off = 32; off > 0; off >>= 1) s += __shfl_xor(s, off);
  if (lane == 0) {
    float4 ps = *(const float4*)&psum[(size_t)row * MSPLIT];
    float term = logf(ps.x + ps.y + ps.z + ps.w) - s * 0.1f;
    part[w] = fminf(term, 92.103403719761827f);   // ratio clip at 1e-40
  }
  __syncthreads();
  if (threadIdx.x == 0)
    blockpart[blockIdx.x] = part[0] + part[1] + part[2] + part[3];
}

// ---- kernel 4: final deterministic reduction ------------------------------
__global__ __launch_bounds__(256) void k_final(const float* __restrict__ blockpart,
                                               float* __restrict__ out) {
  __shared__ float red[256];
  float s = 0.0f;
  for (int i = threadIdx.x; i < (BB * NN) / 4; i += 256) s += blockpart[i];
  red[threadIdx.x] = s;
  __syncthreads();
  for (int st = 128; st > 0; st >>= 1) {
    if (threadIdx.x < st) red[threadIdx.x] += red[threadIdx.x + st];
    __syncthreads();
  }
  if (threadIdx.x == 0) out[0] = red[0] * (1.0f / (BB * NN));
}

extern "C" void kernel_launch(void* const* d_in, const int* in_sizes, int n_in,
                              void* d_out, int out_size, void* d_ws, size_t ws_size,
                              hipStream_t stream) {
  const float* fs = (const float*)d_in[0];
  const float* ft = (const float*)d_in[1];
  float* out = (float*)d_out;

  const size_t NE = (size_t)BB * NN * DD;
  unsigned short* fsb = (unsigned short*)d_ws;                 // 4MB (ftb follows)
  unsigned short* ftb = fsb + NE;                              // 4MB
  float* inv_norm = (float*)(ftb + NE);                        // 64KB
  float* psum     = inv_norm + (size_t)BB * NN;                // B*N*4 f32
  float* pmaxv    = psum + (size_t)BB * NN * MSPLIT;           // B*N*32 f32
  int*   pmaxi    = (int*)(pmaxv + (size_t)BB * NN * NTT);     // B*N*32 i32
  float* blockpart = (float*)(pmaxi + (size_t)BB * NN * NTT);  // B*N/4 f32

  k_prep<<<(2 * BB * NN) / 4, 256, 0, stream>>>(fs, ft, (unsigned*)fsb, inv_norm);
  dim3 g2(NN / BM, MSPLIT, BB);
  k_main<<<g2, 256, 0, stream>>>(fsb, ftb, inv_norm, psum, pmaxv, pmaxi);
  k_post<<<(BB * NN) / 4, 256, 0, stream>>>(fs, ft, psum, pmaxv, pmaxi, blockpart);
  k_final<<<1, 256, 0, stream>>>(blockpart, out);
}